// Round 10
// baseline (606.875 us; speedup 1.0000x reference)
//
#include <hip/hip_runtime.h>
#include <hip/hip_fp16.h>
#include <hip/hip_bf16.h>
#include <math.h>

#define BB 64
#define CC 122
#define TT 500
#define NCOUT 64
#define DD 128
#define HHEADS 8
#define FFDIM 256
#define NLAYER 2
#define EPS 1e-5f
#define SEQ (BB*CC)   // 7808

// ---------------- workspace float offsets ----------------
#define WS_W2T     0u            // 20480 ushort bf16 w2t [kk][co][ci] (20480 floats reserved)
#define WS_S1      20480u
#define WS_SH1     20544u
#define WS_S2      20608u
#define WS_SH2     20672u
#define WS_WBF     20736u        // 262144 ushorts: bf16 qkv/out/ff1/ff2 weights
#define WS_TOK     151808u       // 7808*128 floats
#define WS_QKVB    1151232u      // 7808*256 ushorts (bf16 q,k) = 999424 floats
#define WS_VTB     2150656u      // 64*128*128 ushorts (bf16 v^T, [b][dh][j]) = 524288 floats
#define WS_GTAB    2674944u      // 512 uints: packed f16 (gelu, delta) pairs over [-8,8]
#define WS_W1S     2675968u      // 1024 floats = 2048 ushorts: bf16 w1s[co][k=32], BN-folded
// end = 2676992 floats = 10.7 MB

// WBF internal ushort offsets
#define WB_QKV  0u        // l*49152 + e*128 + k
#define WB_OUT  98304u    // l*16384 + e*128 + k
#define WB_FF1  131072u   // l*32768 + e*128 + k
#define WB_FF2  196608u   // l*32768 + e*256 + k

typedef __attribute__((ext_vector_type(8))) short bf16x8;
typedef __attribute__((ext_vector_type(4))) float f32x4;

__device__ __forceinline__ unsigned short f2bf(float f) {
    unsigned int u = __float_as_uint(f);
    unsigned int r = u + 0x7FFFu + ((u >> 16) & 1u);
    return (unsigned short)(r >> 16);
}

// branch-free erf-GELU (A&S 7.1.26)
__device__ __forceinline__ float gelu_fast(float x) {
    float z = fabsf(x) * 0.70710678118654752f;
    float t = __builtin_amdgcn_rcpf(fmaf(0.3275911f, z, 1.0f));
    float p = fmaf(fmaf(fmaf(fmaf(1.061405429f, t, -1.453152027f), t,
                             1.421413741f), t, -0.284496736f), t, 0.254829592f);
    float e = __expf(-z * z);
    float erf_abs = fmaf(-p * t, e, 1.0f);
    float erf_x = copysignf(erf_abs, x);
    return 0.5f * x * (1.0f + erf_x);
}

// table GELU: 512 packed-f16 (value,delta) pairs over [-8,8]; b32 gather
__device__ __forceinline__ float gelu_tab(float x, const unsigned* __restrict__ gt) {
    float p = fmaf(x, 32.0f, 256.0f);
    p = fminf(fmaxf(p, 0.0f), 511.999f);
    int i = (int)p;
    float fr = p - (float)i;
    unsigned u = gt[i];
    __half2 h2 = *(__half2*)&u;
    float v0 = __half2float(h2.x);
    float d  = __half2float(h2.y);
    return fmaf(fr, d, v0);
}

// ---------------- prep: fold BN, bf16-ify weights, build tables ----------------
__global__ void prep_kernel(const float* __restrict__ conv1_w, const float* __restrict__ conv1_b,
                            const float* __restrict__ bn1_g, const float* __restrict__ bn1_b,
                            const float* __restrict__ bn1_m, const float* __restrict__ bn1_v,
                            const float* __restrict__ conv2_w, const float* __restrict__ conv2_b,
                            const float* __restrict__ bn2_g, const float* __restrict__ bn2_b,
                            const float* __restrict__ bn2_m, const float* __restrict__ bn2_v,
                            const float* __restrict__ qkv_w, const float* __restrict__ out_w,
                            const float* __restrict__ ff1_w, const float* __restrict__ ff2_w,
                            float* __restrict__ ws) {
    int idx = blockIdx.x * blockDim.x + threadIdx.x;
    if (idx < 20480) {
        int ci = idx & 63; int co = (idx >> 6) & 63; int kk = idx >> 12;
        unsigned short* wt = (unsigned short*)(ws + WS_W2T);
        wt[idx] = f2bf(conv2_w[(co*64 + ci)*5 + kk]);
    } else if (idx < 20544) {
        int i = idx - 20480;
        float s = bn1_g[i] * rsqrtf(bn1_v[i] + EPS);
        ws[WS_S1 + i] = s;
        ws[WS_SH1 + i] = (conv1_b[i] - bn1_m[i]) * s + bn1_b[i];
    } else if (idx < 20608) {
        int i = idx - 20544;
        float s = bn2_g[i] * rsqrtf(bn2_v[i] + EPS);
        ws[WS_S2 + i] = s;
        ws[WS_SH2 + i] = (conv2_b[i] - bn2_m[i]) * s + bn2_b[i];
    } else if (idx < 282752) {
        int r = idx - 20608;
        unsigned short* wbf = (unsigned short*)(ws + WS_WBF);
        float v;
        if (r < 98304)       v = qkv_w[r];
        else if (r < 131072) v = out_w[r - 98304];
        else if (r < 196608) v = ff1_w[r - 131072];
        else                 v = ff2_w[r - 196608];
        wbf[r] = f2bf(v);
    } else if (idx < 283264) {
        int i = idx - 282752;
        float x0 = (i - 256) * 0.03125f;
        float x1 = x0 + 0.03125f;
        float g0 = 0.5f*x0*(1.0f + erff(x0*0.70710678118654752f));
        float g1 = 0.5f*x1*(1.0f + erff(x1*0.70710678118654752f));
        __half hv = __float2half_rn(g0);
        __half hd = __float2half_rn(g1 - g0);
        unsigned short uv = *(unsigned short*)&hv;
        unsigned short ud = *(unsigned short*)&hd;
        ((unsigned*)(ws + WS_GTAB))[i] = (unsigned)uv | ((unsigned)ud << 16);
    } else if (idx < 285312) {
        int i = idx - 283264;            // co*32 + k
        int co = i >> 5, k = i & 31;
        unsigned short* w1s = (unsigned short*)(ws + WS_W1S);
        float s = bn1_g[co] * rsqrtf(bn1_v[co] + EPS);
        w1s[i] = (k < 9) ? f2bf(conv1_w[co*9 + k] * s) : (unsigned short)0;
    }
}

// ---------------- fused conv1 [MFMA] + pool + conv2 [MFMA] + mean + proj ----------------
// 512 threads (8 waves) per sequence; LDS ~39.4 KB -> 4 blocks/CU possible = 32 waves/CU.
// launch_bounds min-waves=4 (VGPR cap 128) so the allocator does NOT spill (round-9 lesson:
// min-waves=8 clamped VGPR to 32 and generated 120 MB of scratch traffic).
__global__ __launch_bounds__(512, 4) void conv_kernel(const float* __restrict__ x,
            const float* __restrict__ proj_w, const float* __restrict__ proj_b,
            const float* __restrict__ elec,
            const float* __restrict__ wsr, float* __restrict__ tok) {
    __shared__ __align__(16) unsigned short h1s[264*64];  // 33792 B
    __shared__ __align__(16) unsigned short xbf[544];     // 1088 B
    __shared__ __align__(16) unsigned gtab[512];          // 2048 B (packed f16 pairs)
    __shared__ float part[512];                           // 2048 B
    __shared__ float mean_l[64];                          // 256 B
    int n = blockIdx.x;
    int c = n % CC;
    int tid = threadIdx.x;
    const float* xg = x + (size_t)n * TT;

    if (tid < 544) {
        unsigned short v = 0;
        if (tid >= 4 && tid < 504) v = f2bf(xg[tid-4]);
        xbf[tid] = v;
    }
    if (tid < 128) {
        ((uint4*)gtab)[tid] = ((const uint4*)(wsr + WS_GTAB))[tid];
    }
    for (int idx = tid; idx < 14*64; idx += 512) {
        int rr = idx >> 6;
        int r = (rr < 2) ? rr : (rr - 2 + 252);
        h1s[r*64 + (idx & 63)] = 0;
    }
    __syncthreads();

    int lane = tid & 63;
    int w = tid >> 6;                 // 0..7
    int ln15 = lane & 15, lg = lane >> 4;

    // ---- phase 1: conv1 via MFMA im2col; wave w covers mt = w*4..w*4+3 ----
    {
        const unsigned short* w1s = (const unsigned short*)(wsr + WS_W1S);
        bf16x8 b1f[4];
        float sh1v[4];
#pragma unroll
        for (int nt = 0; nt < 4; nt++) {
            int co = nt*16 + ln15;
            b1f[nt] = *(const bf16x8*)&w1s[co*32 + lg*8];
            sh1v[nt] = wsr[WS_SH1 + co];
        }
#pragma unroll
        for (int mi = 0; mi < 4; mi++) {
            int mt = w*4 + mi;
            int t = mt*16 + ln15;
            short e[8];
#pragma unroll
            for (int j = 0; j < 8; j++) e[j] = (short)xbf[t + lg*8 + j];
            bf16x8 af = {e[0],e[1],e[2],e[3],e[4],e[5],e[6],e[7]};
#pragma unroll
            for (int nt = 0; nt < 4; nt++) {
                f32x4 cacc = __builtin_amdgcn_mfma_f32_16x16x32_bf16(af, b1f[nt],
                                (f32x4){0.f,0.f,0.f,0.f}, 0, 0, 0);
                float g0 = gelu_tab(cacc[0] + sh1v[nt], gtab);
                float g1 = gelu_tab(cacc[1] + sh1v[nt], gtab);
                float g2 = gelu_tab(cacc[2] + sh1v[nt], gtab);
                float g3 = gelu_tab(cacc[3] + sh1v[nt], gtab);
                int tpA = mt*8 + lg*2;
                if (tpA < 250) {
                    int co = nt*16 + ln15;
                    union { __hip_bfloat162 b; unsigned u; } pk;
                    pk.b = __float22bfloat162_rn(make_float2(fmaxf(g0, g1), fmaxf(g2, g3)));
                    int r = tpA + 2;
                    int cp = (co >> 3) ^ (r & 7);
                    h1s[r*64 + cp*8 + (co & 7)] = (unsigned short)(pk.u & 0xffffu);
                    int r2 = r + 1;
                    int cp2 = (co >> 3) ^ (r2 & 7);
                    h1s[r2*64 + cp2*8 + (co & 7)] = (unsigned short)(pk.u >> 16);
                }
            }
        }
    }
    __syncthreads();

    // ---- phase 2: conv2 as 5 shifted GEMMs; wave w covers mt = w*2, w*2+1 ----
    const unsigned short* wt = (const unsigned short*)(wsr + WS_W2T);
    f32x4 acc[2][4];
#pragma unroll
    for (int mi = 0; mi < 2; mi++)
#pragma unroll
        for (int nt = 0; nt < 4; nt++) acc[mi][nt] = (f32x4){0.f, 0.f, 0.f, 0.f};

    const unsigned short* wbase = wt + ln15*64 + lg*8;
#pragma unroll
    for (int kk = 0; kk < 5; kk++) {
#pragma unroll
        for (int s = 0; s < 2; s++) {
            bf16x8 bfv[4];
#pragma unroll
            for (int nt = 0; nt < 4; nt++)
                bfv[nt] = *(const bf16x8*)(wbase + kk*4096 + nt*1024 + s*32);
#pragma unroll
            for (int mi = 0; mi < 2; mi++) {
                int r = (w*2 + mi)*16 + ln15 + kk;
                int cp = (s*4 + lg) ^ (r & 7);
                bf16x8 af = *(const bf16x8*)&h1s[r*64 + cp*8];
#pragma unroll
                for (int nt = 0; nt < 4; nt++)
                    acc[mi][nt] = __builtin_amdgcn_mfma_f32_16x16x32_bf16(af, bfv[nt], acc[mi][nt], 0, 0, 0);
            }
        }
    }

    // ---- epilogue: BN + GELU + mean over t ----
#pragma unroll
    for (int nt = 0; nt < 4; nt++) {
        int co2 = nt*16 + ln15;
        float sc = wsr[WS_S2 + co2], sh = wsr[WS_SH2 + co2];
        float p = 0.f;
#pragma unroll
        for (int mi = 0; mi < 2; mi++) {
            int tbase = (w*2 + mi)*16 + lg*4;
#pragma unroll
            for (int i = 0; i < 4; i++) {
                if (tbase + i < 250)
                    p += gelu_tab(fmaf(acc[mi][nt][i], sc, sh), gtab);
            }
        }
        p += __shfl_down(p, 32, 64);
        p += __shfl_down(p, 16, 64);
        if (lane < 16) part[w*64 + co2] = p;
    }
    __syncthreads();
    if (tid < 64) {
        float s = 0.f;
#pragma unroll
        for (int k = 0; k < 8; k++) s += part[k*64 + tid];
        mean_l[tid] = s * (1.0f/250.0f);
    }
    __syncthreads();

    if (tid < DD) {
        int d = tid;
        float a = proj_b[d] + elec[c*DD + d];
#pragma unroll 8
        for (int o = 0; o < 64; o++) a = fmaf(mean_l[o], proj_w[d*64 + o], a);
        tok[(size_t)n * DD + d] = a;
    }
}

// ---------------- qkv GEMM: tok[f32] @ qkv_w^T + b -> bf16 qkvb (q,k) / vtb (v^T) ----
__global__ __launch_bounds__(256) void qkv_gemm(const float* __restrict__ Aptr,
        const unsigned short* __restrict__ Bbf,   // layer's qkv weights [e][k]
        const float* __restrict__ bias,           // layer's qkv bias [384]
        unsigned short* __restrict__ qkvb,        // [7808][256]
        unsigned short* __restrict__ vtb) {       // [b*128+dh][128]
    const int tid = threadIdx.x;
    const int m0 = blockIdx.x * 32;
    const int y  = blockIdx.y;                    // 0:q 1:k 2:v
    const int n0 = y * 128;
    __shared__ __align__(16) unsigned short As[32*128];

    const float* A = Aptr + (size_t)m0 * 128;
    for (int i = tid; i < 1024; i += 256) {
        int m = i >> 5; int kq = (i & 31)*4;
        float4 v = *(const float4*)(A + m*128 + kq);
        int cp = (kq >> 3) ^ (m & 15);
        short4 s4 = make_short4((short)f2bf(v.x), (short)f2bf(v.y),
                                (short)f2bf(v.z), (short)f2bf(v.w));
        *(short4*)&As[m*128 + cp*8 + (kq & 7)] = s4;
    }
    __syncthreads();

    const int lane = tid & 63, w = tid >> 6;
    const int ln15 = lane & 15, lg = lane >> 4;
    f32x4 acc[2][2];
#pragma unroll
    for (int mi = 0; mi < 2; mi++)
#pragma unroll
        for (int ni = 0; ni < 2; ni++) acc[mi][ni] = (f32x4){0.f, 0.f, 0.f, 0.f};

    const unsigned short* Bb = Bbf + (size_t)n0 * 128;
#pragma unroll
    for (int kt = 0; kt < 4; kt++) {
        bf16x8 af[2], bfv[2];
#pragma unroll
        for (int mi = 0; mi < 2; mi++) {
            int m = mi*16 + ln15;
            int cp = (kt*4 + lg) ^ (m & 15);
            af[mi] = *(const bf16x8*)&As[m*128 + cp*8];
        }
#pragma unroll
        for (int ni = 0; ni < 2; ni++) {
            int nn = (w*2 + ni)*16 + ln15;
            bfv[ni] = *(const bf16x8*)&Bb[(size_t)nn*128 + kt*32 + lg*8];
        }
#pragma unroll
        for (int mi = 0; mi < 2; mi++)
#pragma unroll
            for (int ni = 0; ni < 2; ni++)
                acc[mi][ni] = __builtin_amdgcn_mfma_f32_16x16x32_bf16(af[mi], bfv[ni], acc[mi][ni], 0, 0, 0);
    }

#pragma unroll
    for (int mi = 0; mi < 2; mi++)
#pragma unroll
        for (int ni = 0; ni < 2; ni++) {
            int nloc = (w*2 + ni)*16 + ln15;
            float bb = bias[n0 + nloc];
#pragma unroll
            for (int i = 0; i < 4; i++) {
                int ml = mi*16 + lg*4 + i;
                int nrow = m0 + ml;
                unsigned short us = f2bf(acc[mi][ni][i] + bb);
                if (y < 2) {
                    qkvb[(size_t)nrow*256 + n0 + nloc] = us;
                } else {
                    int bq = nrow / 122;
                    int j  = nrow - bq*122;
                    vtb[((size_t)(bq*128 + nloc))*128 + j] = us;
                }
            }
        }
}

// ---------------- fused attention + out-proj + LN1 + FF + LN2 (512 thr, head/wave) ----
// block = (b, quarter): rows m0l..m0l+31 of batch b; wave w handles head w
__global__ __launch_bounds__(512) void attn_tail(
        const unsigned short* __restrict__ qkvb,
        const unsigned short* __restrict__ vtb,
        const unsigned short* __restrict__ outW, const float* __restrict__ outb,
        float* __restrict__ tok,
        const float* __restrict__ ln1g, const float* __restrict__ ln1b,
        const unsigned short* __restrict__ B1, const float* __restrict__ b1,
        const unsigned short* __restrict__ B2, const float* __restrict__ b2,
        const float* __restrict__ ln2g, const float* __restrict__ ln2b) {
    __shared__ float Cs[32*129];                               // 16.5 KB
    __shared__ __align__(16) unsigned short Pregion[8*16*128]; // 32 KB (P/wave; later ln1buf+Hs)
    __shared__ __align__(16) unsigned short ctxs[32*128];      // 8 KB

    const int tid = threadIdx.x;
    const int blk = blockIdx.x;
    const int b = blk >> 2, mq = blk & 3;
    const int m0l = mq * 32;
    const int lane = tid & 63, w = tid >> 6;       // w = 0..7 = head
    const int ln15 = lane & 15, lg = lane >> 4;

    const unsigned short* qb = qkvb + (size_t)b * 122 * 256;
    unsigned short* Pw = Pregion + w * 2048;       // 16 rows x 128 cols bf16

    // ================= attention: head h = w, two 16-row chunks =================
    {
        const int h = w;
#pragma unroll
        for (int mt = 0; mt < 2; mt++) {
            // Q A-frag (octets k>=16 zeroed)
            int mrow = m0l + mt*16 + ln15;
            int gr = (mrow < 122) ? mrow : 121;
            bf16x8 af = {0,0,0,0,0,0,0,0};
            if (lg < 2) af = *(const bf16x8*)(qb + gr*256 + h*16 + lg*8);
            // S = Q K^T
            f32x4 S[8];
#pragma unroll
            for (int nt = 0; nt < 8; nt++) {
                int j = nt*16 + ln15;
                int gj = (j < 122) ? j : 121;
                bf16x8 bv = {0,0,0,0,0,0,0,0};
                if (lg < 2) bv = *(const bf16x8*)(qb + gj*256 + 128 + h*16 + lg*8);
                S[nt] = __builtin_amdgcn_mfma_f32_16x16x32_bf16(af, bv,
                            (f32x4){0.f,0.f,0.f,0.f}, 0, 0, 0);
            }
            // softmax (row = lg*4+i; reduce over ln15 within 16-lane group)
            float sm[4];
#pragma unroll
            for (int i = 0; i < 4; i++) {
                float m_ = -1e30f;
#pragma unroll
                for (int nt = 0; nt < 8; nt++) {
                    float v = S[nt][i] * 0.25f;
                    if (nt == 7 && ln15 >= 10) v = -1e30f;
                    S[nt][i] = v;
                    m_ = fmaxf(m_, v);
                }
                m_ = fmaxf(m_, __shfl_xor(m_, 1, 64));
                m_ = fmaxf(m_, __shfl_xor(m_, 2, 64));
                m_ = fmaxf(m_, __shfl_xor(m_, 4, 64));
                m_ = fmaxf(m_, __shfl_xor(m_, 8, 64));
                float s_ = 0.f;
#pragma unroll
                for (int nt = 0; nt < 8; nt++) {
                    float e = __expf(S[nt][i] - m_);
                    S[nt][i] = e;
                    s_ += e;
                }
                s_ += __shfl_xor(s_, 1, 64);
                s_ += __shfl_xor(s_, 2, 64);
                s_ += __shfl_xor(s_, 4, 64);
                s_ += __shfl_xor(s_, 8, 64);
                sm[i] = s_;
            }
            // P (unnormalized) -> Pw (16 rows, A-layout)
#pragma unroll
            for (int nt = 0; nt < 8; nt++)
#pragma unroll
                for (int i = 0; i < 4; i++) {
                    int rp = lg*4 + i;
                    int j = nt*16 + ln15;
                    int cp = (j >> 3) ^ rp;
                    Pw[rp*128 + cp*8 + (j & 7)] = f2bf(S[nt][i]);
                }
            // PV (K=128 over j)
            f32x4 cacc = (f32x4){0.f,0.f,0.f,0.f};
#pragma unroll
            for (int kt = 0; kt < 4; kt++) {
                bf16x8 bv = *(const bf16x8*)(vtb + ((size_t)(b*128 + h*16 + ln15))*128 + kt*32 + lg*8);
                int m = ln15;
                int cp = (kt*4 + lg) ^ m;
                bf16x8 ap = *(const bf16x8*)&Pw[m*128 + cp*8];
                cacc = __builtin_amdgcn_mfma_f32_16x16x32_bf16(ap, bv, cacc, 0, 0, 0);
            }
            // normalize + write ctx (bf16, A-layout)
#pragma unroll
            for (int i = 0; i < 4; i++) {
                float inv = __builtin_amdgcn_rcpf(sm[i]);
                int rp = mt*16 + lg*4 + i;
                int ccol = h*16 + ln15;
                int cp = (ccol >> 3) ^ (rp & 15);
                ctxs[rp*128 + cp*8 + (ccol & 7)] = f2bf(cacc[i] * inv);
            }
        }
    }
    __syncthreads();

    // ================= out-proj + residual: wave w owns cols w*16..w*16+15 =================
    {
        f32x4 acc[2];
#pragma unroll
        for (int mi = 0; mi < 2; mi++) acc[mi] = (f32x4){0.f,0.f,0.f,0.f};
        int nn = w*16 + ln15;
#pragma unroll
        for (int kt = 0; kt < 4; kt++) {
            bf16x8 bv = *(const bf16x8*)&outW[(size_t)nn*128 + kt*32 + lg*8];
#pragma unroll
            for (int mi = 0; mi < 2; mi++) {
                int m = mi*16 + ln15;
                int cp = (kt*4 + lg) ^ (m & 15);
                bf16x8 afm = *(const bf16x8*)&ctxs[m*128 + cp*8];
                acc[mi] = __builtin_amdgcn_mfma_f32_16x16x32_bf16(afm, bv, acc[mi], 0, 0, 0);
            }
        }
        float bb = outb[nn];
#pragma unroll
        for (int mi = 0; mi < 2; mi++)
#pragma unroll
            for (int i = 0; i < 4; i++) {
                int ml = mi*16 + lg*4 + i;
                int mrow = m0l + ml;
                int grow = b*122 + ((mrow < 122) ? mrow : 121);
                Cs[ml*129 + nn] = acc[mi][i] + bb + tok[(size_t)grow*128 + nn];
            }
    }
    __syncthreads();

    // ================= LN1 -> Cs(f32) + ln1buf(bf16) =================
    unsigned short* ln1buf = Pregion;          // 8 KB
    unsigned short* Hs = Pregion + 4096;       // 16 KB
    {
        int r = tid >> 4, sub = tid & 15;      // 32 rows x 16 lanes x 8 cols
        float s1 = 0.f, s2 = 0.f;
#pragma unroll
        for (int j = 0; j < 8; j++) {
            float vv = Cs[r*129 + sub*8 + j];
            s1 += vv; s2 += vv*vv;
        }
        s1 += __shfl_xor(s1, 1, 64); s2 += __shfl_xor(s2, 1, 64);
        s1 += __shfl_xor(s1, 2, 64); s2 += __shfl_xor(s2, 2, 64);
        s1 += __shfl_xor(s1, 4, 64); s2 += __shfl_xor(s2, 4, 64);
        s1 += __shfl_xor(s1, 8, 64); s2 += __shfl_xor(s2, 8, 64);
        float mu = s1 * (1.0f/128.0f);
        float var = s2 * (1.0f/128.0f) - mu*mu;
        float rstd = rsqrtf(var + EPS);
#pragma unroll
        for (int j = 0; j < 8; j++) {
            int nloc = sub*8 + j;
            float vv = (Cs[r*129 + nloc] - mu) * rstd * ln1g[nloc] + ln1b[nloc];
            Cs[r*129 + nloc] = vv;
            int cp = (nloc >> 3) ^ (r & 15);
            ln1buf[r*128 + cp*8 + (nloc & 7)] = f2bf(vv);
        }
    }
    __syncthreads();

    // ================= ff1 (gelu) -> Hs: wave w owns cols w*32..w*32+31 =================
    {
        f32x4 acc1[2][2];
#pragma unroll
        for (int mi = 0; mi < 2; mi++)
#pragma unroll
            for (int ni = 0; ni < 2; ni++) acc1[mi][ni] = (f32x4){0.f,0.f,0.f,0.f};
#pragma unroll
        for (int kt = 0; kt < 4; kt++) {
            bf16x8 afm[2];
#pragma unroll
            for (int mi = 0; mi < 2; mi++) {
                int m = mi*16 + ln15;
                int cp = (kt*4 + lg) ^ (m & 15);
                afm[mi] = *(const bf16x8*)&ln1buf[m*128 + cp*8];
            }
#pragma unroll
            for (int ni = 0; ni < 2; ni++) {
                int nn = (w*2 + ni)*16 + ln15;
                bf16x8 bv = *(const bf16x8*)&B1[(size_t)nn*128 + kt*32 + lg*8];
#pragma unroll
                for (int mi = 0; mi < 2; mi++)
                    acc1[mi][ni] = __builtin_amdgcn_mfma_f32_16x16x32_bf16(afm[mi], bv, acc1[mi][ni], 0, 0, 0);
            }
        }
#pragma unroll
        for (int ni = 0; ni < 2; ni++) {
            int nn = (w*2 + ni)*16 + ln15;
            float bb = b1[nn];
#pragma unroll
            for (int mi = 0; mi < 2; mi++)
#pragma unroll
                for (int i = 0; i < 4; i++) {
                    int m = mi*16 + lg*4 + i;
                    float v = gelu_fast(acc1[mi][ni][i] + bb);
                    int cp = (nn >> 3) ^ (m & 15);
                    Hs[m*256 + cp*8 + (nn & 7)] = f2bf(v);
                }
        }
    }
    __syncthreads();

    // ================= ff2 + residual: wave w owns cols w*16..w*16+15 =================
    {
        f32x4 acc2[2];
#pragma unroll
        for (int mi = 0; mi < 2; mi++) acc2[mi] = (f32x4){0.f,0.f,0.f,0.f};
        int nn = w*16 + ln15;
#pragma unroll
        for (int kt = 0; kt < 8; kt++) {
            bf16x8 bv = *(const bf16x8*)&B2[(size_t)nn*256 + kt*32 + lg*8];
#pragma unroll
            for (int mi = 0; mi < 2; mi++) {
                int m = mi*16 + ln15;
                int cp = (kt*4 + lg) ^ (m & 15);
                bf16x8 afm = *(const bf16x8*)&Hs[m*256 + cp*8];
                acc2[mi] = __builtin_amdgcn_mfma_f32_16x16x32_bf16(afm, bv, acc2[mi], 0, 0, 0);
            }
        }
        float bb = b2[nn];
#pragma unroll
        for (int mi = 0; mi < 2; mi++)
#pragma unroll
            for (int i = 0; i < 4; i++) {
                int ml = mi*16 + lg*4 + i;
                Cs[ml*129 + nn] = acc2[mi][i] + bb + Cs[ml*129 + nn];
            }
    }
    __syncthreads();

    // ================= LN2 -> tok =================
    {
        int r = tid >> 4, sub = tid & 15;
        float s1 = 0.f, s2 = 0.f;
#pragma unroll
        for (int j = 0; j < 8; j++) {
            float vv = Cs[r*129 + sub*8 + j];
            s1 += vv; s2 += vv*vv;
        }
        s1 += __shfl_xor(s1, 1, 64); s2 += __shfl_xor(s2, 1, 64);
        s1 += __shfl_xor(s1, 2, 64); s2 += __shfl_xor(s2, 2, 64);
        s1 += __shfl_xor(s1, 4, 64); s2 += __shfl_xor(s2, 4, 64);
        s1 += __shfl_xor(s1, 8, 64); s2 += __shfl_xor(s2, 8, 64);
        float mu = s1 * (1.0f/128.0f);
        float var = s2 * (1.0f/128.0f) - mu*mu;
        float rstd = rsqrtf(var + EPS);
        if (m0l + r < 122) {
#pragma unroll
            for (int j = 0; j < 8; j++) {
                int nloc = sub*8 + j;
                float vv = (Cs[r*129 + nloc] - mu) * rstd * ln2g[nloc] + ln2b[nloc];
                tok[((size_t)(b*122 + m0l + r))*128 + nloc] = vv;
            }
        }
    }
}

// ---------------- final: mean over C + subject head ----------------
__global__ __launch_bounds__(128) void final_kernel(const float* __restrict__ tok,
        const int* __restrict__ sid,
        const float* __restrict__ hw, const float* __restrict__ hb,
        float* __restrict__ outp) {
    __shared__ float pool[DD];
    int b = blockIdx.x, tid = threadIdx.x;
    float s = 0.f;
    for (int c2 = 0; c2 < CC; c2++) s += tok[((size_t)b*CC + c2)*DD + tid];
    pool[tid] = s * (1.0f/(float)CC);
    __syncthreads();
    if (tid < 4) {
        int sb = sid[b];
        const float* w = hw + ((size_t)sb*4 + tid)*DD;
        float a = hb[sb*4 + tid];
#pragma unroll 8
        for (int d = 0; d < DD; d++) a = fmaf(pool[d], w[d], a);
        outp[b*4 + tid] = a;
    }
}

extern "C" void kernel_launch(void* const* d_in, const int* in_sizes, int n_in,
                              void* d_out, int out_size, void* d_ws, size_t ws_size,
                              hipStream_t stream) {
    const float* x       = (const float*)d_in[0];
    const int*   sid     = (const int*)  d_in[1];
    const float* conv1_w = (const float*)d_in[2];
    const float* conv1_b = (const float*)d_in[3];
    const float* bn1_g   = (const float*)d_in[4];
    const float* bn1_b   = (const float*)d_in[5];
    const float* bn1_m   = (const float*)d_in[6];
    const float* bn1_v   = (const float*)d_in[7];
    const float* conv2_w = (const float*)d_in[8];
    const float* conv2_b = (const float*)d_in[9];
    const float* bn2_g   = (const float*)d_in[10];
    const float* bn2_b   = (const float*)d_in[11];
    const float* bn2_m   = (const float*)d_in[12];
    const float* bn2_v   = (const float*)d_in[13];
    const float* proj_w  = (const float*)d_in[14];
    const float* proj_b  = (const float*)d_in[15];
    const float* elec    = (const float*)d_in[16];
    const float* qkv_w   = (const float*)d_in[17];
    const float* qkv_b   = (const float*)d_in[18];
    const float* out_w   = (const float*)d_in[19];
    const float* out_b   = (const float*)d_in[20];
    const float* ln1_g   = (const float*)d_in[21];
    const float* ln1_b   = (const float*)d_in[22];
    const float* ff1_w   = (const float*)d_in[23];
    const float* ff1_b   = (const float*)d_in[24];
    const float* ff2_w   = (const float*)d_in[25];
    const float* ff2_b   = (const float*)d_in[26];
    const float* ln2_g   = (const float*)d_in[27];
    const float* ln2_b   = (const float*)d_in[28];
    const float* heads_w = (const float*)d_in[29];
    const float* heads_b = (const float*)d_in[30];
    float* ws = (float*)d_ws;
    const unsigned short* wbf = (const unsigned short*)(ws + WS_WBF);
    unsigned short* qkvb = (unsigned short*)(ws + WS_QKVB);
    unsigned short* vtb  = (unsigned short*)(ws + WS_VTB);

    prep_kernel<<<(285312 + 255)/256, 256, 0, stream>>>(
        conv1_w, conv1_b, bn1_g, bn1_b, bn1_m, bn1_v,
        conv2_w, conv2_b, bn2_g, bn2_b, bn2_m, bn2_v,
        qkv_w, out_w, ff1_w, ff2_w, ws);

    conv_kernel<<<SEQ, 512, 0, stream>>>(x, proj_w, proj_b, elec, ws, ws + WS_TOK);

    for (int l = 0; l < NLAYER; l++) {
        qkv_gemm<<<dim3(244,3), 256, 0, stream>>>(
            ws + WS_TOK, wbf + WB_QKV + l*49152, qkv_b + l*384, qkvb, vtb);
        attn_tail<<<BB*4, 512, 0, stream>>>(
            qkvb, vtb,
            wbf + WB_OUT + l*16384, out_b + l*128,
            ws + WS_TOK, ln1_g + l*128, ln1_b + l*128,
            wbf + WB_FF1 + l*32768, ff1_b + l*256,
            wbf + WB_FF2 + l*32768, ff2_b + l*128,
            ln2_g + l*128, ln2_b + l*128);
    }

    final_kernel<<<BB, 128, 0, stream>>>(ws + WS_TOK, sid, heads_w, heads_b, (float*)d_out);
}

// Round 11
// 418.188 us; speedup vs baseline: 1.4512x; 1.4512x over previous
//
#include <hip/hip_runtime.h>
#include <hip/hip_fp16.h>
#include <hip/hip_bf16.h>
#include <math.h>

#define BB 64
#define CC 122
#define TT 500
#define NCOUT 64
#define DD 128
#define HHEADS 8
#define FFDIM 256
#define NLAYER 2
#define EPS 1e-5f
#define SEQ (BB*CC)   // 7808

// ---------------- workspace float offsets ----------------
#define WS_W2T     0u            // 20480 ushort bf16 w2t [kk][co][ci] (20480 floats reserved)
#define WS_S1      20480u
#define WS_SH1     20544u
#define WS_S2      20608u
#define WS_SH2     20672u
#define WS_WBF     20736u        // 262144 ushorts: bf16 qkv/out/ff1/ff2 weights
#define WS_TOK     151808u       // 7808*128 floats
#define WS_QKVB    1151232u      // 7808*256 ushorts (bf16 q,k) = 999424 floats
#define WS_VTB     2150656u      // 64*128*128 ushorts (bf16 v^T, [b][dh][j]) = 524288 floats
#define WS_GTAB    2674944u      // 512 uints: packed f16 (gelu, delta) pairs over [-8,8]
#define WS_W1S     2675968u      // 1024 floats: bf16 w1s[co][k=32], BN-folded
#define WS_QKVB2   2676992u      // layer-1 qkv double buffer (999424 floats)
#define WS_VTB2    3676416u      // layer-1 v^T double buffer (524288 floats)
// end = 4200704 floats = 16.8 MB

// WBF internal ushort offsets
#define WB_QKV  0u        // l*49152 + e*128 + k
#define WB_OUT  98304u    // l*16384 + e*128 + k
#define WB_FF1  131072u   // l*32768 + e*128 + k
#define WB_FF2  196608u   // l*32768 + e*256 + k

typedef __attribute__((ext_vector_type(8))) short bf16x8;
typedef __attribute__((ext_vector_type(4))) float f32x4;

__device__ __forceinline__ unsigned short f2bf(float f) {
    unsigned int u = __float_as_uint(f);
    unsigned int r = u + 0x7FFFu + ((u >> 16) & 1u);
    return (unsigned short)(r >> 16);
}

// branch-free erf-GELU (A&S 7.1.26)
__device__ __forceinline__ float gelu_fast(float x) {
    float z = fabsf(x) * 0.70710678118654752f;
    float t = __builtin_amdgcn_rcpf(fmaf(0.3275911f, z, 1.0f));
    float p = fmaf(fmaf(fmaf(fmaf(1.061405429f, t, -1.453152027f), t,
                             1.421413741f), t, -0.284496736f), t, 0.254829592f);
    float e = __expf(-z * z);
    float erf_abs = fmaf(-p * t, e, 1.0f);
    float erf_x = copysignf(erf_abs, x);
    return 0.5f * x * (1.0f + erf_x);
}

// table GELU: 512 packed-f16 (value,delta) pairs over [-8,8]; b32 gather
__device__ __forceinline__ float gelu_tab(float x, const unsigned* __restrict__ gt) {
    float p = fmaf(x, 32.0f, 256.0f);
    p = fminf(fmaxf(p, 0.0f), 511.999f);
    int i = (int)p;
    float fr = p - (float)i;
    unsigned u = gt[i];
    __half2 h2 = *(__half2*)&u;
    float v0 = __half2float(h2.x);
    float d  = __half2float(h2.y);
    return fmaf(fr, d, v0);
}

// ---------------- prep: fold BN, bf16-ify weights, build tables ----------------
__global__ void prep_kernel(const float* __restrict__ conv1_w, const float* __restrict__ conv1_b,
                            const float* __restrict__ bn1_g, const float* __restrict__ bn1_b,
                            const float* __restrict__ bn1_m, const float* __restrict__ bn1_v,
                            const float* __restrict__ conv2_w, const float* __restrict__ conv2_b,
                            const float* __restrict__ bn2_g, const float* __restrict__ bn2_b,
                            const float* __restrict__ bn2_m, const float* __restrict__ bn2_v,
                            const float* __restrict__ qkv_w, const float* __restrict__ out_w,
                            const float* __restrict__ ff1_w, const float* __restrict__ ff2_w,
                            float* __restrict__ ws) {
    int idx = blockIdx.x * blockDim.x + threadIdx.x;
    if (idx < 20480) {
        int ci = idx & 63; int co = (idx >> 6) & 63; int kk = idx >> 12;
        unsigned short* wt = (unsigned short*)(ws + WS_W2T);
        wt[idx] = f2bf(conv2_w[(co*64 + ci)*5 + kk]);
    } else if (idx < 20544) {
        int i = idx - 20480;
        float s = bn1_g[i] * rsqrtf(bn1_v[i] + EPS);
        ws[WS_S1 + i] = s;
        ws[WS_SH1 + i] = (conv1_b[i] - bn1_m[i]) * s + bn1_b[i];
    } else if (idx < 20608) {
        int i = idx - 20544;
        float s = bn2_g[i] * rsqrtf(bn2_v[i] + EPS);
        ws[WS_S2 + i] = s;
        ws[WS_SH2 + i] = (conv2_b[i] - bn2_m[i]) * s + bn2_b[i];
    } else if (idx < 282752) {
        int r = idx - 20608;
        unsigned short* wbf = (unsigned short*)(ws + WS_WBF);
        float v;
        if (r < 98304)       v = qkv_w[r];
        else if (r < 131072) v = out_w[r - 98304];
        else if (r < 196608) v = ff1_w[r - 131072];
        else                 v = ff2_w[r - 196608];
        wbf[r] = f2bf(v);
    } else if (idx < 283264) {
        int i = idx - 282752;
        float x0 = (i - 256) * 0.03125f;
        float x1 = x0 + 0.03125f;
        float g0 = 0.5f*x0*(1.0f + erff(x0*0.70710678118654752f));
        float g1 = 0.5f*x1*(1.0f + erff(x1*0.70710678118654752f));
        __half hv = __float2half_rn(g0);
        __half hd = __float2half_rn(g1 - g0);
        unsigned short uv = *(unsigned short*)&hv;
        unsigned short ud = *(unsigned short*)&hd;
        ((unsigned*)(ws + WS_GTAB))[i] = (unsigned)uv | ((unsigned)ud << 16);
    } else if (idx < 285312) {
        int i = idx - 283264;            // co*32 + k
        int co = i >> 5, k = i & 31;
        unsigned short* w1s = (unsigned short*)(ws + WS_W1S);
        float s = bn1_g[co] * rsqrtf(bn1_v[co] + EPS);
        w1s[i] = (k < 9) ? f2bf(conv1_w[co*9 + k] * s) : (unsigned short)0;
    }
}

// ---------------- fused conv1 [MFMA] + pool + conv2 [MFMA] + mean + proj ----------------
// round-8 config: 256 threads, 4 waves; LDS ~38.4 KB. (512-thr variants regressed: r9 spilled,
// r10 didn't raise occupancy but halved per-wave ILP.)
__global__ __launch_bounds__(256, 4) void conv_kernel(const float* __restrict__ x,
            const float* __restrict__ proj_w, const float* __restrict__ proj_b,
            const float* __restrict__ elec,
            const float* __restrict__ wsr, float* __restrict__ tok) {
    __shared__ __align__(16) unsigned short h1s[264*64];  // 33792 B
    __shared__ __align__(16) unsigned short xbf[544];     // 1088 B
    __shared__ __align__(16) unsigned gtab[512];          // 2048 B (packed f16 pairs)
    __shared__ float part[256];                           // 1024 B
    __shared__ float mean_l[64];                          // 256 B
    int n = blockIdx.x;
    int c = n % CC;
    int tid = threadIdx.x;
    const float* xg = x + (size_t)n * TT;

    for (int i = tid; i < 544; i += 256) {
        unsigned short v = 0;
        if (i >= 4 && i < 504) v = f2bf(xg[i-4]);
        xbf[i] = v;
    }
    if (tid < 128) {
        ((uint4*)gtab)[tid] = ((const uint4*)(wsr + WS_GTAB))[tid];
    }
    for (int idx = tid; idx < 14*64; idx += 256) {
        int rr = idx >> 6;
        int r = (rr < 2) ? rr : (rr - 2 + 252);
        h1s[r*64 + (idx & 63)] = 0;
    }
    __syncthreads();

    int lane = tid & 63;
    int w = tid >> 6;
    int ln15 = lane & 15, lg = lane >> 4;

    // ---- phase 1: conv1 via MFMA im2col (w1s zero-padded k>=9 kills masked taps) ----
    {
        const unsigned short* w1s = (const unsigned short*)(wsr + WS_W1S);
        bf16x8 b1f[4];
        float sh1v[4];
#pragma unroll
        for (int nt = 0; nt < 4; nt++) {
            int co = nt*16 + ln15;
            b1f[nt] = *(const bf16x8*)&w1s[co*32 + lg*8];
            sh1v[nt] = wsr[WS_SH1 + co];
        }
        for (int mi = 0; mi < 8; mi++) {
            int mt = w*8 + mi;
            int t = mt*16 + ln15;
            short e[8];
#pragma unroll
            for (int j = 0; j < 8; j++) e[j] = (short)xbf[t + lg*8 + j];
            bf16x8 af = {e[0],e[1],e[2],e[3],e[4],e[5],e[6],e[7]};
#pragma unroll
            for (int nt = 0; nt < 4; nt++) {
                f32x4 cacc = __builtin_amdgcn_mfma_f32_16x16x32_bf16(af, b1f[nt],
                                (f32x4){0.f,0.f,0.f,0.f}, 0, 0, 0);
                float g0 = gelu_tab(cacc[0] + sh1v[nt], gtab);
                float g1 = gelu_tab(cacc[1] + sh1v[nt], gtab);
                float g2 = gelu_tab(cacc[2] + sh1v[nt], gtab);
                float g3 = gelu_tab(cacc[3] + sh1v[nt], gtab);
                int tpA = mt*8 + lg*2;
                if (tpA < 250) {
                    int co = nt*16 + ln15;
                    union { __hip_bfloat162 b; unsigned u; } pk;
                    pk.b = __float22bfloat162_rn(make_float2(fmaxf(g0, g1), fmaxf(g2, g3)));
                    int r = tpA + 2;
                    int cp = (co >> 3) ^ (r & 7);
                    h1s[r*64 + cp*8 + (co & 7)] = (unsigned short)(pk.u & 0xffffu);
                    int r2 = r + 1;
                    int cp2 = (co >> 3) ^ (r2 & 7);
                    h1s[r2*64 + cp2*8 + (co & 7)] = (unsigned short)(pk.u >> 16);
                }
            }
        }
    }
    __syncthreads();

    // ---- phase 2: conv2 as 5 shifted GEMMs ----
    const unsigned short* wt = (const unsigned short*)(wsr + WS_W2T);
    f32x4 acc[4][4];
#pragma unroll
    for (int mi = 0; mi < 4; mi++)
#pragma unroll
        for (int nt = 0; nt < 4; nt++) acc[mi][nt] = (f32x4){0.f, 0.f, 0.f, 0.f};

    const unsigned short* wbase = wt + ln15*64 + lg*8;
#pragma unroll
    for (int kk = 0; kk < 5; kk++) {
#pragma unroll
        for (int s = 0; s < 2; s++) {
            bf16x8 bfv[4];
#pragma unroll
            for (int nt = 0; nt < 4; nt++)
                bfv[nt] = *(const bf16x8*)(wbase + kk*4096 + nt*1024 + s*32);
#pragma unroll
            for (int mi = 0; mi < 4; mi++) {
                int r = (w*4 + mi)*16 + ln15 + kk;
                int cp = (s*4 + lg) ^ (r & 7);
                bf16x8 af = *(const bf16x8*)&h1s[r*64 + cp*8];
#pragma unroll
                for (int nt = 0; nt < 4; nt++)
                    acc[mi][nt] = __builtin_amdgcn_mfma_f32_16x16x32_bf16(af, bfv[nt], acc[mi][nt], 0, 0, 0);
            }
        }
    }

    // ---- epilogue: BN + GELU + mean over t ----
#pragma unroll
    for (int nt = 0; nt < 4; nt++) {
        int co2 = nt*16 + ln15;
        float sc = wsr[WS_S2 + co2], sh = wsr[WS_SH2 + co2];
        float p = 0.f;
#pragma unroll
        for (int mi = 0; mi < 4; mi++) {
            int tbase = (w*4 + mi)*16 + lg*4;
#pragma unroll
            for (int i = 0; i < 4; i++) {
                if (tbase + i < 250)
                    p += gelu_tab(fmaf(acc[mi][nt][i], sc, sh), gtab);
            }
        }
        p += __shfl_down(p, 32, 64);
        p += __shfl_down(p, 16, 64);
        if (lane < 16) part[w*64 + co2] = p;
    }
    __syncthreads();
    if (tid < 64) {
        mean_l[tid] = (part[tid] + part[64+tid] + part[128+tid] + part[192+tid]) * (1.0f/250.0f);
    }
    __syncthreads();

    if (tid < DD) {
        int d = tid;
        float a = proj_b[d] + elec[c*DD + d];
#pragma unroll 8
        for (int o = 0; o < 64; o++) a = fmaf(mean_l[o], proj_w[d*64 + o], a);
        tok[(size_t)n * DD + d] = a;
    }
}

// ---------------- qkv GEMM (layer 0 only): tok[f32] @ qkv_w^T + b -> bf16 qkvb / vtb ----
__global__ __launch_bounds__(256) void qkv_gemm(const float* __restrict__ Aptr,
        const unsigned short* __restrict__ Bbf,
        const float* __restrict__ bias,
        unsigned short* __restrict__ qkvb,        // [7808][256]
        unsigned short* __restrict__ vtb) {       // [b*128+dh][128]
    const int tid = threadIdx.x;
    const int m0 = blockIdx.x * 32;
    const int y  = blockIdx.y;                    // 0:q 1:k 2:v
    const int n0 = y * 128;
    __shared__ __align__(16) unsigned short As[32*128];

    const float* A = Aptr + (size_t)m0 * 128;
    for (int i = tid; i < 1024; i += 256) {
        int m = i >> 5; int kq = (i & 31)*4;
        float4 v = *(const float4*)(A + m*128 + kq);
        int cp = (kq >> 3) ^ (m & 15);
        short4 s4 = make_short4((short)f2bf(v.x), (short)f2bf(v.y),
                                (short)f2bf(v.z), (short)f2bf(v.w));
        *(short4*)&As[m*128 + cp*8 + (kq & 7)] = s4;
    }
    __syncthreads();

    const int lane = tid & 63, w = tid >> 6;
    const int ln15 = lane & 15, lg = lane >> 4;
    f32x4 acc[2][2];
#pragma unroll
    for (int mi = 0; mi < 2; mi++)
#pragma unroll
        for (int ni = 0; ni < 2; ni++) acc[mi][ni] = (f32x4){0.f, 0.f, 0.f, 0.f};

    const unsigned short* Bb = Bbf + (size_t)n0 * 128;
#pragma unroll
    for (int kt = 0; kt < 4; kt++) {
        bf16x8 af[2], bfv[2];
#pragma unroll
        for (int mi = 0; mi < 2; mi++) {
            int m = mi*16 + ln15;
            int cp = (kt*4 + lg) ^ (m & 15);
            af[mi] = *(const bf16x8*)&As[m*128 + cp*8];
        }
#pragma unroll
        for (int ni = 0; ni < 2; ni++) {
            int nn = (w*2 + ni)*16 + ln15;
            bfv[ni] = *(const bf16x8*)&Bb[(size_t)nn*128 + kt*32 + lg*8];
        }
#pragma unroll
        for (int mi = 0; mi < 2; mi++)
#pragma unroll
            for (int ni = 0; ni < 2; ni++)
                acc[mi][ni] = __builtin_amdgcn_mfma_f32_16x16x32_bf16(af[mi], bfv[ni], acc[mi][ni], 0, 0, 0);
    }

#pragma unroll
    for (int mi = 0; mi < 2; mi++)
#pragma unroll
        for (int ni = 0; ni < 2; ni++) {
            int nloc = (w*2 + ni)*16 + ln15;
            float bb = bias[n0 + nloc];
#pragma unroll
            for (int i = 0; i < 4; i++) {
                int ml = mi*16 + lg*4 + i;
                int nrow = m0 + ml;
                unsigned short us = f2bf(acc[mi][ni][i] + bb);
                if (y < 2) {
                    qkvb[(size_t)nrow*256 + n0 + nloc] = us;
                } else {
                    int bq = nrow / 122;
                    int j  = nrow - bq*122;
                    vtb[((size_t)(bq*128 + nloc))*128 + j] = us;
                }
            }
        }
}

// ---------------- fused attention + out-proj + LN1 + FF + LN2 (+ next-layer qkv) ----------
// block = (b, quarter): rows m0l..m0l+31 of batch b; wave w handles head w.
// do_qkv=1: after LN2, compute next layer's qkv for these rows into qkvb_o/vtb_o
// (double buffer — avoids cross-block RAW race with this launch's attention reads).
__global__ __launch_bounds__(512) void attn_tail(
        const unsigned short* __restrict__ qkvb,
        const unsigned short* __restrict__ vtb,
        const unsigned short* __restrict__ outW, const float* __restrict__ outb,
        float* __restrict__ tok,
        const float* __restrict__ ln1g, const float* __restrict__ ln1b,
        const unsigned short* __restrict__ B1, const float* __restrict__ b1,
        const unsigned short* __restrict__ B2, const float* __restrict__ b2,
        const float* __restrict__ ln2g, const float* __restrict__ ln2b,
        const unsigned short* __restrict__ Bq, const float* __restrict__ bq,
        unsigned short* __restrict__ qkvb_o, unsigned short* __restrict__ vtb_o,
        int do_qkv) {
    __shared__ float Cs[32*129];                               // 16.5 KB
    __shared__ __align__(16) unsigned short Pregion[8*16*128]; // 32 KB (P/wave; later ln1buf+Hs; later qbuf)
    __shared__ __align__(16) unsigned short ctxs[32*128];      // 8 KB

    const int tid = threadIdx.x;
    const int blk = blockIdx.x;
    const int b = blk >> 2, mq = blk & 3;
    const int m0l = mq * 32;
    const int lane = tid & 63, w = tid >> 6;       // w = 0..7 = head
    const int ln15 = lane & 15, lg = lane >> 4;

    const unsigned short* qb = qkvb + (size_t)b * 122 * 256;
    unsigned short* Pw = Pregion + w * 2048;       // 16 rows x 128 cols bf16

    // ================= attention: head h = w, two 16-row chunks =================
    {
        const int h = w;
#pragma unroll
        for (int mt = 0; mt < 2; mt++) {
            int mrow = m0l + mt*16 + ln15;
            int gr = (mrow < 122) ? mrow : 121;
            bf16x8 af = {0,0,0,0,0,0,0,0};
            if (lg < 2) af = *(const bf16x8*)(qb + gr*256 + h*16 + lg*8);
            // S = Q K^T
            f32x4 S[8];
#pragma unroll
            for (int nt = 0; nt < 8; nt++) {
                int j = nt*16 + ln15;
                int gj = (j < 122) ? j : 121;
                bf16x8 bv = {0,0,0,0,0,0,0,0};
                if (lg < 2) bv = *(const bf16x8*)(qb + gj*256 + 128 + h*16 + lg*8);
                S[nt] = __builtin_amdgcn_mfma_f32_16x16x32_bf16(af, bv,
                            (f32x4){0.f,0.f,0.f,0.f}, 0, 0, 0);
            }
            // softmax
            float sm[4];
#pragma unroll
            for (int i = 0; i < 4; i++) {
                float m_ = -1e30f;
#pragma unroll
                for (int nt = 0; nt < 8; nt++) {
                    float v = S[nt][i] * 0.25f;
                    if (nt == 7 && ln15 >= 10) v = -1e30f;
                    S[nt][i] = v;
                    m_ = fmaxf(m_, v);
                }
                m_ = fmaxf(m_, __shfl_xor(m_, 1, 64));
                m_ = fmaxf(m_, __shfl_xor(m_, 2, 64));
                m_ = fmaxf(m_, __shfl_xor(m_, 4, 64));
                m_ = fmaxf(m_, __shfl_xor(m_, 8, 64));
                float s_ = 0.f;
#pragma unroll
                for (int nt = 0; nt < 8; nt++) {
                    float e = __expf(S[nt][i] - m_);
                    S[nt][i] = e;
                    s_ += e;
                }
                s_ += __shfl_xor(s_, 1, 64);
                s_ += __shfl_xor(s_, 2, 64);
                s_ += __shfl_xor(s_, 4, 64);
                s_ += __shfl_xor(s_, 8, 64);
                sm[i] = s_;
            }
            // P -> Pw (16 rows, A-layout)
#pragma unroll
            for (int nt = 0; nt < 8; nt++)
#pragma unroll
                for (int i = 0; i < 4; i++) {
                    int rp = lg*4 + i;
                    int j = nt*16 + ln15;
                    int cp = (j >> 3) ^ rp;
                    Pw[rp*128 + cp*8 + (j & 7)] = f2bf(S[nt][i]);
                }
            // PV
            f32x4 cacc = (f32x4){0.f,0.f,0.f,0.f};
#pragma unroll
            for (int kt = 0; kt < 4; kt++) {
                bf16x8 bv = *(const bf16x8*)(vtb + ((size_t)(b*128 + h*16 + ln15))*128 + kt*32 + lg*8);
                int m = ln15;
                int cp = (kt*4 + lg) ^ m;
                bf16x8 ap = *(const bf16x8*)&Pw[m*128 + cp*8];
                cacc = __builtin_amdgcn_mfma_f32_16x16x32_bf16(ap, bv, cacc, 0, 0, 0);
            }
            // normalize + write ctx (bf16, A-layout)
#pragma unroll
            for (int i = 0; i < 4; i++) {
                float inv = __builtin_amdgcn_rcpf(sm[i]);
                int rp = mt*16 + lg*4 + i;
                int ccol = h*16 + ln15;
                int cp = (ccol >> 3) ^ (rp & 15);
                ctxs[rp*128 + cp*8 + (ccol & 7)] = f2bf(cacc[i] * inv);
            }
        }
    }
    __syncthreads();

    // ================= out-proj + residual: wave w owns cols w*16..w*16+15 =================
    {
        f32x4 acc[2];
#pragma unroll
        for (int mi = 0; mi < 2; mi++) acc[mi] = (f32x4){0.f,0.f,0.f,0.f};
        int nn = w*16 + ln15;
#pragma unroll
        for (int kt = 0; kt < 4; kt++) {
            bf16x8 bv = *(const bf16x8*)&outW[(size_t)nn*128 + kt*32 + lg*8];
#pragma unroll
            for (int mi = 0; mi < 2; mi++) {
                int m = mi*16 + ln15;
                int cp = (kt*4 + lg) ^ (m & 15);
                bf16x8 afm = *(const bf16x8*)&ctxs[m*128 + cp*8];
                acc[mi] = __builtin_amdgcn_mfma_f32_16x16x32_bf16(afm, bv, acc[mi], 0, 0, 0);
            }
        }
        float bb = outb[nn];
#pragma unroll
        for (int mi = 0; mi < 2; mi++)
#pragma unroll
            for (int i = 0; i < 4; i++) {
                int ml = mi*16 + lg*4 + i;
                int mrow = m0l + ml;
                int grow = b*122 + ((mrow < 122) ? mrow : 121);
                Cs[ml*129 + nn] = acc[mi][i] + bb + tok[(size_t)grow*128 + nn];
            }
    }
    __syncthreads();

    // ================= LN1 -> Cs(f32) + ln1buf(bf16) =================
    unsigned short* ln1buf = Pregion;          // 8 KB
    unsigned short* Hs = Pregion + 4096;       // 16 KB
    {
        int r = tid >> 4, sub = tid & 15;      // 32 rows x 16 lanes x 8 cols
        float s1 = 0.f, s2 = 0.f;
#pragma unroll
        for (int j = 0; j < 8; j++) {
            float vv = Cs[r*129 + sub*8 + j];
            s1 += vv; s2 += vv*vv;
        }
        s1 += __shfl_xor(s1, 1, 64); s2 += __shfl_xor(s2, 1, 64);
        s1 += __shfl_xor(s1, 2, 64); s2 += __shfl_xor(s2, 2, 64);
        s1 += __shfl_xor(s1, 4, 64); s2 += __shfl_xor(s2, 4, 64);
        s1 += __shfl_xor(s1, 8, 64); s2 += __shfl_xor(s2, 8, 64);
        float mu = s1 * (1.0f/128.0f);
        float var = s2 * (1.0f/128.0f) - mu*mu;
        float rstd = rsqrtf(var + EPS);
#pragma unroll
        for (int j = 0; j < 8; j++) {
            int nloc = sub*8 + j;
            float vv = (Cs[r*129 + nloc] - mu) * rstd * ln1g[nloc] + ln1b[nloc];
            Cs[r*129 + nloc] = vv;
            int cp = (nloc >> 3) ^ (r & 15);
            ln1buf[r*128 + cp*8 + (nloc & 7)] = f2bf(vv);
        }
    }
    __syncthreads();

    // ================= ff1 (gelu) -> Hs: wave w owns cols w*32..w*32+31 =================
    {
        f32x4 acc1[2][2];
#pragma unroll
        for (int mi = 0; mi < 2; mi++)
#pragma unroll
            for (int ni = 0; ni < 2; ni++) acc1[mi][ni] = (f32x4){0.f,0.f,0.f,0.f};
#pragma unroll
        for (int kt = 0; kt < 4; kt++) {
            bf16x8 afm[2];
#pragma unroll
            for (int mi = 0; mi < 2; mi++) {
                int m = mi*16 + ln15;
                int cp = (kt*4 + lg) ^ (m & 15);
                afm[mi] = *(const bf16x8*)&ln1buf[m*128 + cp*8];
            }
#pragma unroll
            for (int ni = 0; ni < 2; ni++) {
                int nn = (w*2 + ni)*16 + ln15;
                bf16x8 bv = *(const bf16x8*)&B1[(size_t)nn*128 + kt*32 + lg*8];
#pragma unroll
                for (int mi = 0; mi < 2; mi++)
                    acc1[mi][ni] = __builtin_amdgcn_mfma_f32_16x16x32_bf16(afm[mi], bv, acc1[mi][ni], 0, 0, 0);
            }
        }
#pragma unroll
        for (int ni = 0; ni < 2; ni++) {
            int nn = (w*2 + ni)*16 + ln15;
            float bb = b1[nn];
#pragma unroll
            for (int mi = 0; mi < 2; mi++)
#pragma unroll
                for (int i = 0; i < 4; i++) {
                    int m = mi*16 + lg*4 + i;
                    float v = gelu_fast(acc1[mi][ni][i] + bb);
                    int cp = (nn >> 3) ^ (m & 15);
                    Hs[m*256 + cp*8 + (nn & 7)] = f2bf(v);
                }
        }
    }
    __syncthreads();

    // ================= ff2 + residual: wave w owns cols w*16..w*16+15 =================
    {
        f32x4 acc2[2];
#pragma unroll
        for (int mi = 0; mi < 2; mi++) acc2[mi] = (f32x4){0.f,0.f,0.f,0.f};
        int nn = w*16 + ln15;
#pragma unroll
        for (int kt = 0; kt < 8; kt++) {
            bf16x8 bv = *(const bf16x8*)&B2[(size_t)nn*256 + kt*32 + lg*8];
#pragma unroll
            for (int mi = 0; mi < 2; mi++) {
                int m = mi*16 + ln15;
                int cp = (kt*4 + lg) ^ (m & 15);
                bf16x8 afm = *(const bf16x8*)&Hs[m*256 + cp*8];
                acc2[mi] = __builtin_amdgcn_mfma_f32_16x16x32_bf16(afm, bv, acc2[mi], 0, 0, 0);
            }
        }
        float bb = b2[nn];
#pragma unroll
        for (int mi = 0; mi < 2; mi++)
#pragma unroll
            for (int i = 0; i < 4; i++) {
                int ml = mi*16 + lg*4 + i;
                Cs[ml*129 + nn] = acc2[mi][i] + bb + Cs[ml*129 + nn];
            }
    }
    __syncthreads();

    // ================= LN2 -> tok (+ qbuf staging for next-layer qkv) =================
    {
        int r = tid >> 4, sub = tid & 15;
        float s1 = 0.f, s2 = 0.f;
#pragma unroll
        for (int j = 0; j < 8; j++) {
            float vv = Cs[r*129 + sub*8 + j];
            s1 += vv; s2 += vv*vv;
        }
        s1 += __shfl_xor(s1, 1, 64); s2 += __shfl_xor(s2, 1, 64);
        s1 += __shfl_xor(s1, 2, 64); s2 += __shfl_xor(s2, 2, 64);
        s1 += __shfl_xor(s1, 4, 64); s2 += __shfl_xor(s2, 4, 64);
        s1 += __shfl_xor(s1, 8, 64); s2 += __shfl_xor(s2, 8, 64);
        float mu = s1 * (1.0f/128.0f);
        float var = s2 * (1.0f/128.0f) - mu*mu;
        float rstd = rsqrtf(var + EPS);
        bool rowok = (m0l + r < 122);
#pragma unroll
        for (int j = 0; j < 8; j++) {
            int nloc = sub*8 + j;
            float vv = (Cs[r*129 + nloc] - mu) * rstd * ln2g[nloc] + ln2b[nloc];
            if (rowok)
                tok[((size_t)(b*122 + m0l + r))*128 + nloc] = vv;
            if (do_qkv) {
                int cp = (nloc >> 3) ^ (r & 15);
                Pregion[r*128 + cp*8 + (nloc & 7)] = f2bf(vv);
            }
        }
    }

    // ================= next-layer qkv: M=32, N=384, K=128; wave w owns cols w*48.. =====
    if (do_qkv) {
        __syncthreads();
        const unsigned short* qbuf = Pregion;
        f32x4 accq[2][3];
#pragma unroll
        for (int mi = 0; mi < 2; mi++)
#pragma unroll
            for (int ni = 0; ni < 3; ni++) accq[mi][ni] = (f32x4){0.f,0.f,0.f,0.f};
#pragma unroll
        for (int kt = 0; kt < 4; kt++) {
            bf16x8 afm[2];
#pragma unroll
            for (int mi = 0; mi < 2; mi++) {
                int m = mi*16 + ln15;
                int cp = (kt*4 + lg) ^ (m & 15);
                afm[mi] = *(const bf16x8*)&qbuf[m*128 + cp*8];
            }
#pragma unroll
            for (int ni = 0; ni < 3; ni++) {
                int e = w*48 + ni*16 + ln15;
                bf16x8 bv = *(const bf16x8*)&Bq[(size_t)e*128 + kt*32 + lg*8];
#pragma unroll
                for (int mi = 0; mi < 2; mi++)
                    accq[mi][ni] = __builtin_amdgcn_mfma_f32_16x16x32_bf16(afm[mi], bv, accq[mi][ni], 0, 0, 0);
            }
        }
#pragma unroll
        for (int ni = 0; ni < 3; ni++) {
            int e = w*48 + ni*16 + ln15;
            float bb = bq[e];
#pragma unroll
            for (int mi = 0; mi < 2; mi++)
#pragma unroll
                for (int i = 0; i < 4; i++) {
                    int ml = mi*16 + lg*4 + i;
                    int mrow = m0l + ml;
                    if (mrow < 122) {
                        unsigned short us = f2bf(accq[mi][ni][i] + bb);
                        int nrow = b*122 + mrow;
                        if (e < 256)
                            qkvb_o[(size_t)nrow*256 + e] = us;
                        else
                            vtb_o[((size_t)(b*128 + (e - 256)))*128 + mrow] = us;
                    }
                }
        }
    }
}

// ---------------- final: mean over C + subject head ----------------
__global__ __launch_bounds__(128) void final_kernel(const float* __restrict__ tok,
        const int* __restrict__ sid,
        const float* __restrict__ hw, const float* __restrict__ hb,
        float* __restrict__ outp) {
    __shared__ float pool[DD];
    int b = blockIdx.x, tid = threadIdx.x;
    float s = 0.f;
    for (int c2 = 0; c2 < CC; c2++) s += tok[((size_t)b*CC + c2)*DD + tid];
    pool[tid] = s * (1.0f/(float)CC);
    __syncthreads();
    if (tid < 4) {
        int sb = sid[b];
        const float* w = hw + ((size_t)sb*4 + tid)*DD;
        float a = hb[sb*4 + tid];
#pragma unroll 8
        for (int d = 0; d < DD; d++) a = fmaf(pool[d], w[d], a);
        outp[b*4 + tid] = a;
    }
}

extern "C" void kernel_launch(void* const* d_in, const int* in_sizes, int n_in,
                              void* d_out, int out_size, void* d_ws, size_t ws_size,
                              hipStream_t stream) {
    const float* x       = (const float*)d_in[0];
    const int*   sid     = (const int*)  d_in[1];
    const float* conv1_w = (const float*)d_in[2];
    const float* conv1_b = (const float*)d_in[3];
    const float* bn1_g   = (const float*)d_in[4];
    const float* bn1_b   = (const float*)d_in[5];
    const float* bn1_m   = (const float*)d_in[6];
    const float* bn1_v   = (const float*)d_in[7];
    const float* conv2_w = (const float*)d_in[8];
    const float* conv2_b = (const float*)d_in[9];
    const float* bn2_g   = (const float*)d_in[10];
    const float* bn2_b   = (const float*)d_in[11];
    const float* bn2_m   = (const float*)d_in[12];
    const float* bn2_v   = (const float*)d_in[13];
    const float* proj_w  = (const float*)d_in[14];
    const float* proj_b  = (const float*)d_in[15];
    const float* elec    = (const float*)d_in[16];
    const float* qkv_w   = (const float*)d_in[17];
    const float* qkv_b   = (const float*)d_in[18];
    const float* out_w   = (const float*)d_in[19];
    const float* out_b   = (const float*)d_in[20];
    const float* ln1_g   = (const float*)d_in[21];
    const float* ln1_b   = (const float*)d_in[22];
    const float* ff1_w   = (const float*)d_in[23];
    const float* ff1_b   = (const float*)d_in[24];
    const float* ff2_w   = (const float*)d_in[25];
    const float* ff2_b   = (const float*)d_in[26];
    const float* ln2_g   = (const float*)d_in[27];
    const float* ln2_b   = (const float*)d_in[28];
    const float* heads_w = (const float*)d_in[29];
    const float* heads_b = (const float*)d_in[30];
    float* ws = (float*)d_ws;
    const unsigned short* wbf = (const unsigned short*)(ws + WS_WBF);
    unsigned short* qkvb  = (unsigned short*)(ws + WS_QKVB);
    unsigned short* vtb   = (unsigned short*)(ws + WS_VTB);
    unsigned short* qkvb2 = (unsigned short*)(ws + WS_QKVB2);
    unsigned short* vtb2  = (unsigned short*)(ws + WS_VTB2);

    prep_kernel<<<(285312 + 255)/256, 256, 0, stream>>>(
        conv1_w, conv1_b, bn1_g, bn1_b, bn1_m, bn1_v,
        conv2_w, conv2_b, bn2_g, bn2_b, bn2_m, bn2_v,
        qkv_w, out_w, ff1_w, ff2_w, ws);

    conv_kernel<<<SEQ, 256, 0, stream>>>(x, proj_w, proj_b, elec, ws, ws + WS_TOK);

    // layer-0 qkv
    qkv_gemm<<<dim3(244,3), 256, 0, stream>>>(
        ws + WS_TOK, wbf + WB_QKV, qkv_b, qkvb, vtb);

    // layer 0 (emits layer-1 qkv into double buffers)
    attn_tail<<<BB*4, 512, 0, stream>>>(
        qkvb, vtb,
        wbf + WB_OUT, out_b,
        ws + WS_TOK, ln1_g, ln1_b,
        wbf + WB_FF1, ff1_b,
        wbf + WB_FF2, ff2_b,
        ln2_g, ln2_b,
        wbf + WB_QKV + 49152, qkv_b + 384, qkvb2, vtb2, 1);

    // layer 1 (no next layer)
    attn_tail<<<BB*4, 512, 0, stream>>>(
        qkvb2, vtb2,
        wbf + WB_OUT + 16384, out_b + 128,
        ws + WS_TOK, ln1_g + 128, ln1_b + 128,
        wbf + WB_FF1 + 32768, ff1_b + 256,
        wbf + WB_FF2 + 32768, ff2_b + 128,
        ln2_g + 128, ln2_b + 128,
        wbf + WB_QKV, qkv_b, qkvb2, vtb2, 0);

    final_kernel<<<BB, 128, 0, stream>>>(ws + WS_TOK, sid, heads_w, heads_b, (float*)d_out);
}